// Round 1
// 534.856 us; speedup vs baseline: 1.0932x; 1.0932x over previous
//
#include <hip/hip_runtime.h>
#include <hip/hip_bf16.h>

#define LL 2048
#define DD 64

typedef __attribute__((ext_vector_type(4))) float f32x4;
typedef __attribute__((ext_vector_type(8))) short short8;
typedef __attribute__((ext_vector_type(4))) short short4v;

#define S1 0.18033688011112042f   /* 0.125 * log2(e) */
#define S2 23.083120654223414f    /* 16 * log2(e) */

static __device__ __forceinline__ short f2bf(float f) {
    union { float f; unsigned u; } v; v.f = f;
    unsigned r = v.u + 0x7fffu + ((v.u >> 16) & 1u);
    return (short)(r >> 16);
}
static __device__ __forceinline__ unsigned pack2(float a, float b) {
    return (unsigned)(unsigned short)f2bf(a) | ((unsigned)(unsigned short)f2bf(b) << 16);
}
static __device__ __forceinline__ float bfu_lo(unsigned u) {
    union { unsigned u; float f; } v; v.u = u << 16; return v.f;
}
static __device__ __forceinline__ float bfu_hi(unsigned u) {
    union { unsigned u; float f; } v; v.u = u & 0xffff0000u; return v.f;
}

// ---------------- prep: fp32 -> bf16 (Q, K) ----------------
__global__ __launch_bounds__(256)
void prep_cvt(const float* __restrict__ Q, const float* __restrict__ K,
              short* __restrict__ Qb, short* __restrict__ Kb) {
    const float* src = blockIdx.y ? K : Q;
    short* dst = blockIdx.y ? Kb : Qb;
    size_t i = ((size_t)blockIdx.x * 256 + threadIdx.x) * 4;
    f32x4 v = *(const f32x4*)(src + i);
    short4v o;
    o[0] = f2bf(v[0]); o[1] = f2bf(v[1]); o[2] = f2bf(v[2]); o[3] = f2bf(v[3]);
    *(short4v*)(dst + i) = o;
}

// ---------------- prep: V [bh][s][d] -> Vt bf16 [bh][d][s] ----------------
__global__ __launch_bounds__(256)
void prep_vt(const float* __restrict__ V, short* __restrict__ Vt) {
    const int bh = blockIdx.y;
    const int s0 = blockIdx.x * 64;
    const int sl = threadIdx.x & 63;
    const int d0 = threadIdx.x >> 6;
    const float* Vs = V + (size_t)bh * LL * DD;
    short* Vd = Vt + (size_t)bh * DD * LL;
#pragma unroll
    for (int i = 0; i < 16; ++i) {
        int d = d0 + i * 4;
        Vd[(size_t)d * LL + s0 + sl] = f2bf(Vs[(size_t)(s0 + sl) * DD + d]);
    }
}

// ---------------- Kernel B: out2 = softmax(QQ^T/8) + softmax(KK^T/8) ----------------
// 8 waves: waves 0-3 QQ^T (col quarters), waves 4-7 KK^T. 16 rows per workgroup.
// Fixed-offset softmax exp(s-16); scores kept as packed-bf16 slab (64 VGPRs).
// Epilogue: KK writes chunk to LDS, QQ RMW-adds, all 512 threads stream out
// full-128B-line float4 nontemporal stores (avoids partial-line RMW at L2/HBM).
//
// launch_bounds(512, 2): 128-VGPR budget. (512,4) forced a 64-VGPR budget which
// spilled the 64-reg slab to scratch -> +274 MB scratch writes + 177 MB reads
// per dispatch (WRITE_SIZE was 2.09x ideal). Measured occupancy was only 44.8%
// anyway, so the 16-waves/CU cap costs nothing real.
__global__ __launch_bounds__(512, 2)
void attnw_kernel(const short* __restrict__ Qb, const short* __restrict__ Kb,
                  float* __restrict__ out2) {
    const int bh = blockIdx.y;
    const int r0 = blockIdx.x * 16;
    const int tid = threadIdx.x;
    const int lane = tid & 63;
    const int wid = tid >> 6;     // 0..7
    const int mat = wid >> 2;     // 0: QQ^T, 1: KK^T
    const int cw  = wid & 3;      // column quarter
    const int q   = lane >> 4;
    const int c0  = lane & 15;
    const int colbase = cw * 512;

    __shared__ float redsum[8][16];
    __shared__ float sbuf[4][16][132];   // [seg][row][col], pad 132 -> 2-way max on RMW

    const short* X = (mat ? Kb : Qb) + (size_t)bh * LL * DD;

    const short8 a0 = *(const short8*)(X + (size_t)(r0 + c0) * DD + q * 8);
    const short8 a1 = *(const short8*)(X + (size_t)(r0 + c0) * DD + 32 + q * 8);

    unsigned slab[64];
    float sum[4] = {0.f, 0.f, 0.f, 0.f};
#pragma unroll
    for (int ct = 0; ct < 32; ++ct) {
        const short* Bp = X + (size_t)(colbase + ct * 16 + c0) * DD + q * 8;
        short8 b0 = *(const short8*)Bp;
        short8 b1 = *(const short8*)(Bp + 32);
        f32x4 z = {0.f, 0.f, 0.f, 0.f};
        z = __builtin_amdgcn_mfma_f32_16x16x32_bf16(a0, b0, z, 0, 0, 0);
        z = __builtin_amdgcn_mfma_f32_16x16x32_bf16(a1, b1, z, 0, 0, 0);
        float e0 = __builtin_amdgcn_exp2f(z[0] * S1 - S2);
        float e1 = __builtin_amdgcn_exp2f(z[1] * S1 - S2);
        float e2 = __builtin_amdgcn_exp2f(z[2] * S1 - S2);
        float e3 = __builtin_amdgcn_exp2f(z[3] * S1 - S2);
        sum[0] += e0; sum[1] += e1; sum[2] += e2; sum[3] += e3;
        slab[2 * ct]     = pack2(e0, e1);
        slab[2 * ct + 1] = pack2(e2, e3);
    }

    // ---- row-sum reduce within wave (16 col-lanes), then cross-wave via LDS ----
#pragma unroll
    for (int off = 1; off < 16; off <<= 1)
#pragma unroll
        for (int r = 0; r < 4; ++r) sum[r] += __shfl_xor(sum[r], off, 64);
    if (c0 == 0) {
#pragma unroll
        for (int r = 0; r < 4; ++r) redsum[wid][q * 4 + r] = sum[r];
    }
    __syncthreads();
    const int mb = mat * 4;
    float rcl[4];
#pragma unroll
    for (int r = 0; r < 4; ++r) {
        int rr = q * 4 + r;
        rcl[r] = 1.0f / (redsum[mb + 0][rr] + redsum[mb + 1][rr] +
                         redsum[mb + 2][rr] + redsum[mb + 3][rr]);
    }

    // ---- per-chunk: KK writes LDS, QQ adds, cooperative full-line stream ----
    float* outp = out2 + (size_t)bh * LL * LL;
#pragma unroll
    for (int ch = 0; ch < 4; ++ch) {
        if (mat == 1) {
#pragma unroll
            for (int t = 0; t < 8; ++t) {
                int ct = ch * 8 + t;
                unsigned u0 = slab[2 * ct], u1 = slab[2 * ct + 1];
                sbuf[cw][q * 4 + 0][t * 16 + c0] = bfu_lo(u0) * rcl[0];
                sbuf[cw][q * 4 + 1][t * 16 + c0] = bfu_hi(u0) * rcl[1];
                sbuf[cw][q * 4 + 2][t * 16 + c0] = bfu_lo(u1) * rcl[2];
                sbuf[cw][q * 4 + 3][t * 16 + c0] = bfu_hi(u1) * rcl[3];
            }
        }
        __syncthreads();
        if (mat == 0) {
#pragma unroll
            for (int t = 0; t < 8; ++t) {
                int ct = ch * 8 + t;
                unsigned u0 = slab[2 * ct], u1 = slab[2 * ct + 1];
                sbuf[cw][q * 4 + 0][t * 16 + c0] += bfu_lo(u0) * rcl[0];
                sbuf[cw][q * 4 + 1][t * 16 + c0] += bfu_hi(u0) * rcl[1];
                sbuf[cw][q * 4 + 2][t * 16 + c0] += bfu_lo(u1) * rcl[2];
                sbuf[cw][q * 4 + 3][t * 16 + c0] += bfu_hi(u1) * rcl[3];
            }
        }
        __syncthreads();
        // stream 16 rows x 512 cols (4 segs of 128): lane -> float4; 32 lanes = 512B/row
#pragma unroll
        for (int it = 0; it < 4; ++it) {
            int idx = tid + it * 512;       // float4 index, 0..2047
            int seg = idx >> 9;             // 0..3
            int rc  = idx & 511;
            int row = rc >> 5;              // 0..15
            int c4  = rc & 31;              // 0..31
            f32x4 v = *(const f32x4*)(&sbuf[seg][row][c4 * 4]);
            __builtin_nontemporal_store(
                v, (f32x4*)&outp[(size_t)(r0 + row) * LL + seg * 512 + ch * 128 + c4 * 4]);
        }
        __syncthreads();
    }
}

// ---------------- Kernel 1: out1 = softmax(QK^T/8) V, fully online ----------------
// 4 waves, 16 Q rows per workgroup; wave cw owns S-cols [cw*512, cw*512+512).
__global__ __launch_bounds__(256, 4)
void sdpa_kernel(const short* __restrict__ Qb, const short* __restrict__ Kb,
                 const short* __restrict__ Vt, float* __restrict__ out1) {
    const int bh = blockIdx.y;
    const int r0 = blockIdx.x * 16;
    const int tid = threadIdx.x;
    const int lane = tid & 63;
    const int cw = tid >> 6;   // 0..3
    const int q = lane >> 4;
    const int c0 = lane & 15;
    const int colbase = cw * 512;

    __shared__ float redsum[4][16];
    __shared__ __align__(16) short pbuf[4][16][40];   // [wave][m][k], row stride 80B
    __shared__ float obuf[4][1024];

    const short* Qh = Qb + (size_t)bh * LL * DD;
    const short* Kh = Kb + (size_t)bh * LL * DD;
    const short* Vh = Vt + (size_t)bh * DD * LL;

    const short8 a0 = *(const short8*)(Qh + (size_t)(r0 + c0) * DD + q * 8);
    const short8 a1 = *(const short8*)(Qh + (size_t)(r0 + c0) * DD + 32 + q * 8);

    f32x4 oacc[4];
#pragma unroll
    for (int dt = 0; dt < 4; ++dt) { f32x4 z = {0.f,0.f,0.f,0.f}; oacc[dt] = z; }
    float sum[4] = {0.f, 0.f, 0.f, 0.f};

#pragma unroll 4
    for (int sb = 0; sb < 16; ++sb) {
        const int sglob = colbase + sb * 32;
        // scores for 16x32 block -> exp -> bf16 into pbuf (A-frag source layout)
#pragma unroll
        for (int h = 0; h < 2; ++h) {
            const short* Bp = Kh + (size_t)(sglob + h * 16 + c0) * DD + q * 8;
            short8 b0 = *(const short8*)Bp;
            short8 b1 = *(const short8*)(Bp + 32);
            f32x4 z = {0.f, 0.f, 0.f, 0.f};
            z = __builtin_amdgcn_mfma_f32_16x16x32_bf16(a0, b0, z, 0, 0, 0);
            z = __builtin_amdgcn_mfma_f32_16x16x32_bf16(a1, b1, z, 0, 0, 0);
#pragma unroll
            for (int r = 0; r < 4; ++r) {
                float e = __builtin_amdgcn_exp2f(z[r] * S1);
                sum[r] += e;
                pbuf[cw][q * 4 + r][h * 16 + c0] = f2bf(e);
            }
        }
        // read back as A-frag (wave-internal LDS round-trip, in-order per wave)
        short8 ap = *(const short8*)(&pbuf[cw][c0][q * 8]);
        // V B-frags from transposed bf16 Vt: contiguous 16B per lane
#pragma unroll
        for (int dt = 0; dt < 4; ++dt) {
            short8 bv = *(const short8*)(Vh + (size_t)(dt * 16 + c0) * LL + sglob + q * 8);
            oacc[dt] = __builtin_amdgcn_mfma_f32_16x16x32_bf16(ap, bv, oacc[dt], 0, 0, 0);
        }
    }

    // ---- cross-wave row-sum ----
#pragma unroll
    for (int off = 1; off < 16; off <<= 1)
#pragma unroll
        for (int r = 0; r < 4; ++r) sum[r] += __shfl_xor(sum[r], off, 64);
    if (c0 == 0) {
#pragma unroll
        for (int r = 0; r < 4; ++r) redsum[cw][q * 4 + r] = sum[r];
    }
    __syncthreads();
    float rcl[4];
#pragma unroll
    for (int r = 0; r < 4; ++r) {
        int rr = q * 4 + r;
        rcl[r] = 1.0f / (redsum[0][rr] + redsum[1][rr] + redsum[2][rr] + redsum[3][rr]);
    }

    // ---- cross-wave output reduction (normalized partials) ----
#pragma unroll
    for (int dt = 0; dt < 4; ++dt)
#pragma unroll
        for (int r = 0; r < 4; ++r)
            obuf[cw][(q * 4 + r) * 64 + dt * 16 + c0] = oacc[dt][r] * rcl[r];
    __syncthreads();
    float* o1 = out1 + (size_t)bh * LL * DD + (size_t)r0 * DD;
    {
        int e4 = tid;  // 256 float4 = 1024 floats
        f32x4 v = *(const f32x4*)(&obuf[0][e4 * 4]);
        f32x4 v1 = *(const f32x4*)(&obuf[1][e4 * 4]);
        f32x4 v2 = *(const f32x4*)(&obuf[2][e4 * 4]);
        f32x4 v3 = *(const f32x4*)(&obuf[3][e4 * 4]);
        v = v + v1 + v2 + v3;
        *(f32x4*)(o1 + e4 * 4) = v;
    }
}

extern "C" void kernel_launch(void* const* d_in, const int* in_sizes, int n_in,
                              void* d_out, int out_size, void* d_ws, size_t ws_size,
                              hipStream_t stream) {
    const float* Q = (const float*)d_in[0];
    const float* K = (const float*)d_in[1];
    const float* V = (const float*)d_in[2];
    float* out1 = (float*)d_out;                          // [2,8,2048,64]
    float* out2 = out1 + (size_t)16 * LL * DD;            // [2,8,2048,2048]

    const size_t N = (size_t)16 * LL * DD;                // 2,097,152 per tensor
    short* Qb = (short*)d_ws;
    short* Kb = Qb + N;
    short* Vt = Kb + N;

    prep_cvt<<<dim3((unsigned)(N / 1024), 2), 256, 0, stream>>>(Q, K, Qb, Kb);
    prep_vt<<<dim3(LL / 64, 16), 256, 0, stream>>>(V, Vt);

    dim3 grid(LL / 16, 16);
    sdpa_kernel<<<grid, 256, 0, stream>>>(Qb, Kb, Vt, out1);
    attnw_kernel<<<grid, 512, 0, stream>>>(Qb, Kb, out2);
}

// Round 2
// 531.662 us; speedup vs baseline: 1.0998x; 1.0060x over previous
//
#include <hip/hip_runtime.h>
#include <hip/hip_bf16.h>

#define LL 2048
#define DD 64

typedef __attribute__((ext_vector_type(4))) float f32x4;
typedef __attribute__((ext_vector_type(8))) short short8;
typedef __attribute__((ext_vector_type(4))) short short4v;

#define S1 0.18033688011112042f   /* 0.125 * log2(e) */
#define S2 23.083120654223414f    /* 16 * log2(e) */

static __device__ __forceinline__ short f2bf(float f) {
    union { float f; unsigned u; } v; v.f = f;
    unsigned r = v.u + 0x7fffu + ((v.u >> 16) & 1u);
    return (short)(r >> 16);
}
static __device__ __forceinline__ unsigned pack2(float a, float b) {
    return (unsigned)(unsigned short)f2bf(a) | ((unsigned)(unsigned short)f2bf(b) << 16);
}
static __device__ __forceinline__ float bfu_lo(unsigned u) {
    union { unsigned u; float f; } v; v.u = u << 16; return v.f;
}
static __device__ __forceinline__ float bfu_hi(unsigned u) {
    union { unsigned u; float f; } v; v.u = u & 0xffff0000u; return v.f;
}

// ---------------- prep: fp32 -> bf16 (Q, K) ----------------
__global__ __launch_bounds__(256)
void prep_cvt(const float* __restrict__ Q, const float* __restrict__ K,
              short* __restrict__ Qb, short* __restrict__ Kb) {
    const float* src = blockIdx.y ? K : Q;
    short* dst = blockIdx.y ? Kb : Qb;
    size_t i = ((size_t)blockIdx.x * 256 + threadIdx.x) * 4;
    f32x4 v = *(const f32x4*)(src + i);
    short4v o;
    o[0] = f2bf(v[0]); o[1] = f2bf(v[1]); o[2] = f2bf(v[2]); o[3] = f2bf(v[3]);
    *(short4v*)(dst + i) = o;
}

// ---------------- prep: V [bh][s][d] -> Vt bf16 [bh][d][s] ----------------
__global__ __launch_bounds__(256)
void prep_vt(const float* __restrict__ V, short* __restrict__ Vt) {
    const int bh = blockIdx.y;
    const int s0 = blockIdx.x * 64;
    const int sl = threadIdx.x & 63;
    const int d0 = threadIdx.x >> 6;
    const float* Vs = V + (size_t)bh * LL * DD;
    short* Vd = Vt + (size_t)bh * DD * LL;
#pragma unroll
    for (int i = 0; i < 16; ++i) {
        int d = d0 + i * 4;
        Vd[(size_t)d * LL + s0 + sl] = f2bf(Vs[(size_t)(s0 + sl) * DD + d]);
    }
}

// ---------------- Kernel B: out2 = softmax(QQ^T/8) + softmax(KK^T/8) ----------------
// Column-split restructure (r2): each of 8 waves owns a 256-col slice and computes
// BOTH its QQ^T and KK^T scores (same total MFMA/exp as the old matrix-split), so
// the softmax(QQ)+softmax(KK) combine happens IN-REGISTER in the owning wave.
// Removes the old epilogue's 12 barriers + KK-write/QQ-RMW phase serialization:
// only 1 barrier remains (row-sum exchange). Stores stay full-128B-line f32x4 nt
// via a wave-PRIVATE double-buffered LDS slab (no cross-wave hazards, chunk n+1
// LDS fill overlaps chunk n stores).
// launch_bounds(512,2): 128-VGPR budget; slab is 64 u32 + 16 frag VGPRs (~115).
// (512,4)'s 64-VGPR budget would spill the slab to scratch (r0 lesson: +274 MB).
__global__ __launch_bounds__(512, 2)
void attnw_kernel(const short* __restrict__ Qb, const short* __restrict__ Kb,
                  float* __restrict__ out2) {
    const int bh = blockIdx.y;
    const int r0 = blockIdx.x * 16;
    const int tid = threadIdx.x;
    const int lane = tid & 63;
    const int w = tid >> 6;       // 0..7: column-slice owner
    const int q = lane >> 4;
    const int c0 = lane & 15;
    const int colbase = w * 256;

    __shared__ float redQ[8][16];
    __shared__ float redK[8][16];
    // [dbuf][wave][row][col] — row stride 68: 4*68 % 32 == 16 -> 2-way max (free)
    __shared__ float sbuf[2][8][16][68];

    const short* Qh = Qb + (size_t)bh * LL * DD;
    const short* Kh = Kb + (size_t)bh * LL * DD;

    const short8 aq0 = *(const short8*)(Qh + (size_t)(r0 + c0) * DD + q * 8);
    const short8 aq1 = *(const short8*)(Qh + (size_t)(r0 + c0) * DD + 32 + q * 8);
    const short8 ak0 = *(const short8*)(Kh + (size_t)(r0 + c0) * DD + q * 8);
    const short8 ak1 = *(const short8*)(Kh + (size_t)(r0 + c0) * DD + 32 + q * 8);

    unsigned slabQ[32];
    unsigned slabK[32];
    float sumQ[4] = {0.f, 0.f, 0.f, 0.f};
    float sumK[4] = {0.f, 0.f, 0.f, 0.f};

    // ---- QQ^T scores for this wave's 16x256 slice ----
#pragma unroll
    for (int ct = 0; ct < 16; ++ct) {
        const short* Bp = Qh + (size_t)(colbase + ct * 16 + c0) * DD + q * 8;
        short8 b0 = *(const short8*)Bp;
        short8 b1 = *(const short8*)(Bp + 32);
        f32x4 z = {0.f, 0.f, 0.f, 0.f};
        z = __builtin_amdgcn_mfma_f32_16x16x32_bf16(aq0, b0, z, 0, 0, 0);
        z = __builtin_amdgcn_mfma_f32_16x16x32_bf16(aq1, b1, z, 0, 0, 0);
        float e0 = __builtin_amdgcn_exp2f(z[0] * S1 - S2);
        float e1 = __builtin_amdgcn_exp2f(z[1] * S1 - S2);
        float e2 = __builtin_amdgcn_exp2f(z[2] * S1 - S2);
        float e3 = __builtin_amdgcn_exp2f(z[3] * S1 - S2);
        sumQ[0] += e0; sumQ[1] += e1; sumQ[2] += e2; sumQ[3] += e3;
        slabQ[2 * ct]     = pack2(e0, e1);
        slabQ[2 * ct + 1] = pack2(e2, e3);
    }
    // ---- KK^T scores for the same slice ----
#pragma unroll
    for (int ct = 0; ct < 16; ++ct) {
        const short* Bp = Kh + (size_t)(colbase + ct * 16 + c0) * DD + q * 8;
        short8 b0 = *(const short8*)Bp;
        short8 b1 = *(const short8*)(Bp + 32);
        f32x4 z = {0.f, 0.f, 0.f, 0.f};
        z = __builtin_amdgcn_mfma_f32_16x16x32_bf16(ak0, b0, z, 0, 0, 0);
        z = __builtin_amdgcn_mfma_f32_16x16x32_bf16(ak1, b1, z, 0, 0, 0);
        float e0 = __builtin_amdgcn_exp2f(z[0] * S1 - S2);
        float e1 = __builtin_amdgcn_exp2f(z[1] * S1 - S2);
        float e2 = __builtin_amdgcn_exp2f(z[2] * S1 - S2);
        float e3 = __builtin_amdgcn_exp2f(z[3] * S1 - S2);
        sumK[0] += e0; sumK[1] += e1; sumK[2] += e2; sumK[3] += e3;
        slabK[2 * ct]     = pack2(e0, e1);
        slabK[2 * ct + 1] = pack2(e2, e3);
    }

    // ---- row-sum reduce within wave (16 col-lanes), then cross-wave via LDS ----
#pragma unroll
    for (int off = 1; off < 16; off <<= 1)
#pragma unroll
        for (int r = 0; r < 4; ++r) {
            sumQ[r] += __shfl_xor(sumQ[r], off, 64);
            sumK[r] += __shfl_xor(sumK[r], off, 64);
        }
    if (c0 == 0) {
#pragma unroll
        for (int r = 0; r < 4; ++r) {
            redQ[w][q * 4 + r] = sumQ[r];
            redK[w][q * 4 + r] = sumK[r];
        }
    }
    __syncthreads();
    float rclQ[4], rclK[4];
#pragma unroll
    for (int r = 0; r < 4; ++r) {
        int rr = q * 4 + r;
        float sq = 0.f, sk = 0.f;
#pragma unroll
        for (int i = 0; i < 8; ++i) { sq += redQ[i][rr]; sk += redK[i][rr]; }
        rclQ[r] = 1.0f / sq;
        rclK[r] = 1.0f / sk;
    }

    // ---- epilogue: wave-private dbuf slab, no barriers ----
    float* outp = out2 + (size_t)bh * LL * LL + (size_t)r0 * LL + colbase;
#pragma unroll
    for (int ch = 0; ch < 4; ++ch) {
        const int buf = ch & 1;
#pragma unroll
        for (int t = 0; t < 4; ++t) {
            int ct = ch * 4 + t;
            unsigned uq0 = slabQ[2 * ct], uq1 = slabQ[2 * ct + 1];
            unsigned uk0 = slabK[2 * ct], uk1 = slabK[2 * ct + 1];
            sbuf[buf][w][q * 4 + 0][t * 16 + c0] = bfu_lo(uq0) * rclQ[0] + bfu_lo(uk0) * rclK[0];
            sbuf[buf][w][q * 4 + 1][t * 16 + c0] = bfu_hi(uq0) * rclQ[1] + bfu_hi(uk0) * rclK[1];
            sbuf[buf][w][q * 4 + 2][t * 16 + c0] = bfu_lo(uq1) * rclQ[2] + bfu_lo(uk1) * rclK[2];
            sbuf[buf][w][q * 4 + 3][t * 16 + c0] = bfu_hi(uq1) * rclQ[3] + bfu_hi(uk1) * rclK[3];
        }
        // stream 16 rows x 64 cols: full 128B lines, 4 f32x4 per lane
#pragma unroll
        for (int it = 0; it < 4; ++it) {
            int idx = lane + it * 64;       // 0..255
            int row = idx >> 4;             // 0..15
            int c4  = idx & 15;             // 0..15
            f32x4 v = *(const f32x4*)(&sbuf[buf][w][row][c4 * 4]);
            __builtin_nontemporal_store(
                v, (f32x4*)&outp[(size_t)row * LL + ch * 64 + c4 * 4]);
        }
    }
}

// ---------------- Kernel 1: out1 = softmax(QK^T/8) V, fully online ----------------
// 4 waves, 16 Q rows per workgroup; wave cw owns S-cols [cw*512, cw*512+512).
__global__ __launch_bounds__(256, 4)
void sdpa_kernel(const short* __restrict__ Qb, const short* __restrict__ Kb,
                 const short* __restrict__ Vt, float* __restrict__ out1) {
    const int bh = blockIdx.y;
    const int r0 = blockIdx.x * 16;
    const int tid = threadIdx.x;
    const int lane = tid & 63;
    const int cw = tid >> 6;   // 0..3
    const int q = lane >> 4;
    const int c0 = lane & 15;
    const int colbase = cw * 512;

    __shared__ float redsum[4][16];
    __shared__ __align__(16) short pbuf[4][16][40];   // [wave][m][k], row stride 80B
    __shared__ float obuf[4][1024];

    const short* Qh = Qb + (size_t)bh * LL * DD;
    const short* Kh = Kb + (size_t)bh * LL * DD;
    const short* Vh = Vt + (size_t)bh * DD * LL;

    const short8 a0 = *(const short8*)(Qh + (size_t)(r0 + c0) * DD + q * 8);
    const short8 a1 = *(const short8*)(Qh + (size_t)(r0 + c0) * DD + 32 + q * 8);

    f32x4 oacc[4];
#pragma unroll
    for (int dt = 0; dt < 4; ++dt) { f32x4 z = {0.f,0.f,0.f,0.f}; oacc[dt] = z; }
    float sum[4] = {0.f, 0.f, 0.f, 0.f};

#pragma unroll 4
    for (int sb = 0; sb < 16; ++sb) {
        const int sglob = colbase + sb * 32;
        // scores for 16x32 block -> exp -> bf16 into pbuf (A-frag source layout)
#pragma unroll
        for (int h = 0; h < 2; ++h) {
            const short* Bp = Kh + (size_t)(sglob + h * 16 + c0) * DD + q * 8;
            short8 b0 = *(const short8*)Bp;
            short8 b1 = *(const short8*)(Bp + 32);
            f32x4 z = {0.f, 0.f, 0.f, 0.f};
            z = __builtin_amdgcn_mfma_f32_16x16x32_bf16(a0, b0, z, 0, 0, 0);
            z = __builtin_amdgcn_mfma_f32_16x16x32_bf16(a1, b1, z, 0, 0, 0);
#pragma unroll
            for (int r = 0; r < 4; ++r) {
                float e = __builtin_amdgcn_exp2f(z[r] * S1);
                sum[r] += e;
                pbuf[cw][q * 4 + r][h * 16 + c0] = f2bf(e);
            }
        }
        // read back as A-frag (wave-internal LDS round-trip, in-order per wave)
        short8 ap = *(const short8*)(&pbuf[cw][c0][q * 8]);
        // V B-frags from transposed bf16 Vt: contiguous 16B per lane
#pragma unroll
        for (int dt = 0; dt < 4; ++dt) {
            short8 bv = *(const short8*)(Vh + (size_t)(dt * 16 + c0) * LL + sglob + q * 8);
            oacc[dt] = __builtin_amdgcn_mfma_f32_16x16x32_bf16(ap, bv, oacc[dt], 0, 0, 0);
        }
    }

    // ---- cross-wave row-sum ----
#pragma unroll
    for (int off = 1; off < 16; off <<= 1)
#pragma unroll
        for (int r = 0; r < 4; ++r) sum[r] += __shfl_xor(sum[r], off, 64);
    if (c0 == 0) {
#pragma unroll
        for (int r = 0; r < 4; ++r) redsum[cw][q * 4 + r] = sum[r];
    }
    __syncthreads();
    float rcl[4];
#pragma unroll
    for (int r = 0; r < 4; ++r) {
        int rr = q * 4 + r;
        rcl[r] = 1.0f / (redsum[0][rr] + redsum[1][rr] + redsum[2][rr] + redsum[3][rr]);
    }

    // ---- cross-wave output reduction (normalized partials) ----
#pragma unroll
    for (int dt = 0; dt < 4; ++dt)
#pragma unroll
        for (int r = 0; r < 4; ++r)
            obuf[cw][(q * 4 + r) * 64 + dt * 16 + c0] = oacc[dt][r] * rcl[r];
    __syncthreads();
    float* o1 = out1 + (size_t)bh * LL * DD + (size_t)r0 * DD;
    {
        int e4 = tid;  // 256 float4 = 1024 floats
        f32x4 v = *(const f32x4*)(&obuf[0][e4 * 4]);
        f32x4 v1 = *(const f32x4*)(&obuf[1][e4 * 4]);
        f32x4 v2 = *(const f32x4*)(&obuf[2][e4 * 4]);
        f32x4 v3 = *(const f32x4*)(&obuf[3][e4 * 4]);
        v = v + v1 + v2 + v3;
        *(f32x4*)(o1 + e4 * 4) = v;
    }
}

extern "C" void kernel_launch(void* const* d_in, const int* in_sizes, int n_in,
                              void* d_out, int out_size, void* d_ws, size_t ws_size,
                              hipStream_t stream) {
    const float* Q = (const float*)d_in[0];
    const float* K = (const float*)d_in[1];
    const float* V = (const float*)d_in[2];
    float* out1 = (float*)d_out;                          // [2,8,2048,64]
    float* out2 = out1 + (size_t)16 * LL * DD;            // [2,8,2048,2048]

    const size_t N = (size_t)16 * LL * DD;                // 2,097,152 per tensor
    short* Qb = (short*)d_ws;
    short* Kb = Qb + N;
    short* Vt = Kb + N;

    prep_cvt<<<dim3((unsigned)(N / 1024), 2), 256, 0, stream>>>(Q, K, Qb, Kb);
    prep_vt<<<dim3(LL / 64, 16), 256, 0, stream>>>(V, Vt);

    dim3 grid(LL / 16, 16);
    sdpa_kernel<<<grid, 256, 0, stream>>>(Qb, Kb, Vt, out1);
    attnw_kernel<<<grid, 512, 0, stream>>>(Qb, Kb, out2);
}

// Round 3
// 455.859 us; speedup vs baseline: 1.2827x; 1.1663x over previous
//
#include <hip/hip_runtime.h>
#include <hip/hip_bf16.h>

#define LL 2048
#define DD 64

typedef __attribute__((ext_vector_type(4))) float f32x4;
typedef __attribute__((ext_vector_type(8))) short short8;
typedef __attribute__((ext_vector_type(4))) short short4v;

#define S1 0.18033688011112042f   /* 0.125 * log2(e) */
#define S2 23.083120654223414f    /* 16 * log2(e) */

static __device__ __forceinline__ short f2bf(float f) {
    union { float f; unsigned u; } v; v.f = f;
    unsigned r = v.u + 0x7fffu + ((v.u >> 16) & 1u);
    return (short)(r >> 16);
}

// ---------------- prep: fp32 -> bf16 (Q, K) ----------------
__global__ __launch_bounds__(256)
void prep_cvt(const float* __restrict__ Q, const float* __restrict__ K,
              short* __restrict__ Qb, short* __restrict__ Kb) {
    const float* src = blockIdx.y ? K : Q;
    short* dst = blockIdx.y ? Kb : Qb;
    size_t i = ((size_t)blockIdx.x * 256 + threadIdx.x) * 4;
    f32x4 v = *(const f32x4*)(src + i);
    short4v o;
    o[0] = f2bf(v[0]); o[1] = f2bf(v[1]); o[2] = f2bf(v[2]); o[3] = f2bf(v[3]);
    *(short4v*)(dst + i) = o;
}

// ---------------- prep: V [bh][s][d] -> Vt bf16 [bh][d][s] ----------------
__global__ __launch_bounds__(256)
void prep_vt(const float* __restrict__ V, short* __restrict__ Vt) {
    const int bh = blockIdx.y;
    const int s0 = blockIdx.x * 64;
    const int sl = threadIdx.x & 63;
    const int d0 = threadIdx.x >> 6;
    const float* Vs = V + (size_t)bh * LL * DD;
    short* Vd = Vt + (size_t)bh * DD * LL;
#pragma unroll
    for (int i = 0; i < 16; ++i) {
        int d = d0 + i * 4;
        Vd[(size_t)d * LL + s0 + sl] = f2bf(Vs[(size_t)(s0 + sl) * DD + d]);
    }
}

// ================= out2 two-pass =================
// r2 post-mortem: the single-pass kernel was pinned at ~185us regardless of
// barrier structure; common factor = 64-reg score slab (92 VGPR -> 4 waves/EU
// cap) + 8x B-panel re-read per 16-row wg (~1 GB L2-side). The slab only
// exists to bridge the softmax row-sum dependency -> split into sums pass +
// recompute/write pass. MFMA was at 3.7% so recompute is free.
// Sums are parked in out1 (S writes, W reads, sdpa overwrites LAST) so no
// assumption about ws_size is needed.

// ---- Kernel S: row sums of exp(X X^T / 8 - 16), X in {Q, K} ----
// wg: 128 rows x 2048 cols, 8 waves (wave = 16 rows). B staged in LDS,
// XOR-swizzled (slot = c*8 + (dd ^ (c&7))) so both the linear 16B/thread
// ds_write and the 16-lane-per-column ds_read_b128 are bank-balanced.
__global__ __launch_bounds__(512, 4)
void attnw_sums(const short* __restrict__ Qb, const short* __restrict__ Kb,
                float* __restrict__ Ssum) {
    const int bh = blockIdx.y;
    const int mat = blockIdx.z;
    const int r0 = blockIdx.x * 128;
    const int tid = threadIdx.x;
    const int lane = tid & 63;
    const int wid = tid >> 6;   // 0..7
    const int q = lane >> 4;
    const int c0 = lane & 15;

    __shared__ short8 stg[512];   // 64 cols x 64 d, swizzled

    const short* X = (mat ? Kb : Qb) + (size_t)bh * LL * DD;
    float* Sd = Ssum + ((size_t)mat * 16 + bh) * LL;

    const int rw = r0 + wid * 16;
    const short8 a0 = *(const short8*)(X + (size_t)(rw + c0) * DD + q * 8);
    const short8 a1 = *(const short8*)(X + (size_t)(rw + c0) * DD + 32 + q * 8);

    const int sc = tid >> 3;        // staging col 0..63
    const int sd = tid & 7;         // staging d-octet 0..7
    const int sslot = sc * 8 + (sd ^ (sc & 7));

    float sum[4] = {0.f, 0.f, 0.f, 0.f};
    short8 rst = *(const short8*)(X + (size_t)sc * DD + sd * 8);
    for (int i = 0; i < 32; ++i) {
        __syncthreads();
        stg[sslot] = rst;
        __syncthreads();
        if (i + 1 < 32)
            rst = *(const short8*)(X + (size_t)((i + 1) * 64 + sc) * DD + sd * 8);
#pragma unroll
        for (int h = 0; h < 4; ++h) {
            const int col = h * 16 + c0;
            short8 b0 = stg[col * 8 + (q ^ (c0 & 7))];
            short8 b1 = stg[col * 8 + ((q + 4) ^ (c0 & 7))];
            f32x4 z = {0.f, 0.f, 0.f, 0.f};
            z = __builtin_amdgcn_mfma_f32_16x16x32_bf16(a0, b0, z, 0, 0, 0);
            z = __builtin_amdgcn_mfma_f32_16x16x32_bf16(a1, b1, z, 0, 0, 0);
#pragma unroll
            for (int r = 0; r < 4; ++r)
                sum[r] += __builtin_amdgcn_exp2f(z[r] * S1 - S2);
        }
    }
#pragma unroll
    for (int off = 1; off < 16; off <<= 1)
#pragma unroll
        for (int r = 0; r < 4; ++r) sum[r] += __shfl_xor(sum[r], off, 64);
    if (c0 == 0) {
#pragma unroll
        for (int r = 0; r < 4; ++r) Sd[rw + q * 4 + r] = sum[r];
    }
}

// ---- Kernel W: out2 = exp(QQ^T/8-16)*rclQ + exp(KK^T/8-16)*rclK ----
// wg: 64 rows x 2048 cols, 4 waves (wave = 16 rows). No score retention:
// compute 32-col chunk -> normalize -> full-128B-line nt stores via a
// wave-private LDS bounce. Stage loads for chunk i+1 issued before the
// compute of chunk i (latency hidden under MFMA+exp).
__global__ __launch_bounds__(256, 4)
void attnw_write(const short* __restrict__ Qb, const short* __restrict__ Kb,
                 const float* __restrict__ Ssum, float* __restrict__ out2) {
    const int bh = blockIdx.y;
    const int r0 = blockIdx.x * 64;
    const int tid = threadIdx.x;
    const int lane = tid & 63;
    const int wid = tid >> 6;   // 0..3
    const int q = lane >> 4;
    const int c0 = lane & 15;

    __shared__ short8 stgQ[256];               // 32 cols x 64 d, swizzled
    __shared__ short8 stgK[256];
    __shared__ __align__(16) float ob[4][16][36];   // wave-private bounce

    const short* Qh = Qb + (size_t)bh * LL * DD;
    const short* Kh = Kb + (size_t)bh * LL * DD;
    const float* Sq = Ssum + (size_t)bh * LL;
    const float* Sk = Ssum + (size_t)(16 + bh) * LL;

    const int rw = r0 + wid * 16;
    const short8 aq0 = *(const short8*)(Qh + (size_t)(rw + c0) * DD + q * 8);
    const short8 aq1 = *(const short8*)(Qh + (size_t)(rw + c0) * DD + 32 + q * 8);
    const short8 ak0 = *(const short8*)(Kh + (size_t)(rw + c0) * DD + q * 8);
    const short8 ak1 = *(const short8*)(Kh + (size_t)(rw + c0) * DD + 32 + q * 8);

    float rclQ[4], rclK[4];
#pragma unroll
    for (int r = 0; r < 4; ++r) {
        rclQ[r] = 1.0f / Sq[rw + q * 4 + r];
        rclK[r] = 1.0f / Sk[rw + q * 4 + r];
    }

    const int sc = tid >> 3;   // staging col 0..31
    const int sd = tid & 7;
    const int sslot = sc * 8 + (sd ^ (sc & 7));

    float* outp = out2 + (size_t)bh * LL * LL + (size_t)rw * LL;

    short8 rq = *(const short8*)(Qh + (size_t)sc * DD + sd * 8);
    short8 rk = *(const short8*)(Kh + (size_t)sc * DD + sd * 8);
    for (int i = 0; i < 64; ++i) {
        __syncthreads();
        stgQ[sslot] = rq;
        stgK[sslot] = rk;
        __syncthreads();
        if (i + 1 < 64) {
            rq = *(const short8*)(Qh + (size_t)((i + 1) * 32 + sc) * DD + sd * 8);
            rk = *(const short8*)(Kh + (size_t)((i + 1) * 32 + sc) * DD + sd * 8);
        }
#pragma unroll
        for (int h = 0; h < 2; ++h) {
            const int col = h * 16 + c0;
            short8 bq0 = stgQ[col * 8 + (q ^ (c0 & 7))];
            short8 bq1 = stgQ[col * 8 + ((q + 4) ^ (c0 & 7))];
            short8 bk0 = stgK[col * 8 + (q ^ (c0 & 7))];
            short8 bk1 = stgK[col * 8 + ((q + 4) ^ (c0 & 7))];
            f32x4 zq = {0.f, 0.f, 0.f, 0.f}, zk = {0.f, 0.f, 0.f, 0.f};
            zq = __builtin_amdgcn_mfma_f32_16x16x32_bf16(aq0, bq0, zq, 0, 0, 0);
            zq = __builtin_amdgcn_mfma_f32_16x16x32_bf16(aq1, bq1, zq, 0, 0, 0);
            zk = __builtin_amdgcn_mfma_f32_16x16x32_bf16(ak0, bk0, zk, 0, 0, 0);
            zk = __builtin_amdgcn_mfma_f32_16x16x32_bf16(ak1, bk1, zk, 0, 0, 0);
#pragma unroll
            for (int r = 0; r < 4; ++r) {
                float v = __builtin_amdgcn_exp2f(zq[r] * S1 - S2) * rclQ[r]
                        + __builtin_amdgcn_exp2f(zk[r] * S1 - S2) * rclK[r];
                ob[wid][q * 4 + r][h * 16 + c0] = v;
            }
        }
        // wave-private bounce -> 16 rows x 32 cols = full 128B lines
#pragma unroll
        for (int j = 0; j < 2; ++j) {
            int idx = lane + j * 64;
            int row = idx >> 3;
            int c8 = idx & 7;
            f32x4 v = *(const f32x4*)(&ob[wid][row][c8 * 4]);
            __builtin_nontemporal_store(
                v, (f32x4*)&outp[(size_t)row * LL + i * 32 + c8 * 4]);
        }
    }
}

// ---------------- Kernel 1: out1 = softmax(QK^T/8) V, fully online ----------------
// 4 waves, 16 Q rows per workgroup; wave cw owns S-cols [cw*512, cw*512+512).
__global__ __launch_bounds__(256, 4)
void sdpa_kernel(const short* __restrict__ Qb, const short* __restrict__ Kb,
                 const short* __restrict__ Vt, float* __restrict__ out1) {
    const int bh = blockIdx.y;
    const int r0 = blockIdx.x * 16;
    const int tid = threadIdx.x;
    const int lane = tid & 63;
    const int cw = tid >> 6;   // 0..3
    const int q = lane >> 4;
    const int c0 = lane & 15;
    const int colbase = cw * 512;

    __shared__ float redsum[4][16];
    __shared__ __align__(16) short pbuf[4][16][40];   // [wave][m][k], row stride 80B
    __shared__ float obuf[4][1024];

    const short* Qh = Qb + (size_t)bh * LL * DD;
    const short* Kh = Kb + (size_t)bh * LL * DD;
    const short* Vh = Vt + (size_t)bh * DD * LL;

    const short8 a0 = *(const short8*)(Qh + (size_t)(r0 + c0) * DD + q * 8);
    const short8 a1 = *(const short8*)(Qh + (size_t)(r0 + c0) * DD + 32 + q * 8);

    f32x4 oacc[4];
#pragma unroll
    for (int dt = 0; dt < 4; ++dt) { f32x4 z = {0.f,0.f,0.f,0.f}; oacc[dt] = z; }
    float sum[4] = {0.f, 0.f, 0.f, 0.f};

#pragma unroll 4
    for (int sb = 0; sb < 16; ++sb) {
        const int sglob = colbase + sb * 32;
        // scores for 16x32 block -> exp -> bf16 into pbuf (A-frag source layout)
#pragma unroll
        for (int h = 0; h < 2; ++h) {
            const short* Bp = Kh + (size_t)(sglob + h * 16 + c0) * DD + q * 8;
            short8 b0 = *(const short8*)Bp;
            short8 b1 = *(const short8*)(Bp + 32);
            f32x4 z = {0.f, 0.f, 0.f, 0.f};
            z = __builtin_amdgcn_mfma_f32_16x16x32_bf16(a0, b0, z, 0, 0, 0);
            z = __builtin_amdgcn_mfma_f32_16x16x32_bf16(a1, b1, z, 0, 0, 0);
#pragma unroll
            for (int r = 0; r < 4; ++r) {
                float e = __builtin_amdgcn_exp2f(z[r] * S1);
                sum[r] += e;
                pbuf[cw][q * 4 + r][h * 16 + c0] = f2bf(e);
            }
        }
        // read back as A-frag (wave-internal LDS round-trip, in-order per wave)
        short8 ap = *(const short8*)(&pbuf[cw][c0][q * 8]);
        // V B-frags from transposed bf16 Vt: contiguous 16B per lane
#pragma unroll
        for (int dt = 0; dt < 4; ++dt) {
            short8 bv = *(const short8*)(Vh + (size_t)(dt * 16 + c0) * LL + sglob + q * 8);
            oacc[dt] = __builtin_amdgcn_mfma_f32_16x16x32_bf16(ap, bv, oacc[dt], 0, 0, 0);
        }
    }

    // ---- cross-wave row-sum ----
#pragma unroll
    for (int off = 1; off < 16; off <<= 1)
#pragma unroll
        for (int r = 0; r < 4; ++r) sum[r] += __shfl_xor(sum[r], off, 64);
    if (c0 == 0) {
#pragma unroll
        for (int r = 0; r < 4; ++r) redsum[cw][q * 4 + r] = sum[r];
    }
    __syncthreads();
    float rcl[4];
#pragma unroll
    for (int r = 0; r < 4; ++r) {
        int rr = q * 4 + r;
        rcl[r] = 1.0f / (redsum[0][rr] + redsum[1][rr] + redsum[2][rr] + redsum[3][rr]);
    }

    // ---- cross-wave output reduction (normalized partials) ----
#pragma unroll
    for (int dt = 0; dt < 4; ++dt)
#pragma unroll
        for (int r = 0; r < 4; ++r)
            obuf[cw][(q * 4 + r) * 64 + dt * 16 + c0] = oacc[dt][r] * rcl[r];
    __syncthreads();
    float* o1 = out1 + (size_t)bh * LL * DD + (size_t)r0 * DD;
    {
        int e4 = tid;  // 256 float4 = 1024 floats
        f32x4 v = *(const f32x4*)(&obuf[0][e4 * 4]);
        f32x4 v1 = *(const f32x4*)(&obuf[1][e4 * 4]);
        f32x4 v2 = *(const f32x4*)(&obuf[2][e4 * 4]);
        f32x4 v3 = *(const f32x4*)(&obuf[3][e4 * 4]);
        v = v + v1 + v2 + v3;
        *(f32x4*)(o1 + e4 * 4) = v;
    }
}

extern "C" void kernel_launch(void* const* d_in, const int* in_sizes, int n_in,
                              void* d_out, int out_size, void* d_ws, size_t ws_size,
                              hipStream_t stream) {
    const float* Q = (const float*)d_in[0];
    const float* K = (const float*)d_in[1];
    const float* V = (const float*)d_in[2];
    float* out1 = (float*)d_out;                          // [2,8,2048,64]
    float* out2 = out1 + (size_t)16 * LL * DD;            // [2,8,2048,2048]

    const size_t N = (size_t)16 * LL * DD;                // 2,097,152 per tensor
    short* Qb = (short*)d_ws;
    short* Kb = Qb + N;
    short* Vt = Kb + N;

    // Row sums live in the out1 region: attnw_sums writes 256 KB, attnw_write
    // reads it, then sdpa_kernel (launched LAST) overwrites out1 entirely.
    float* Ssum = out1;

    prep_cvt<<<dim3((unsigned)(N / 1024), 2), 256, 0, stream>>>(Q, K, Qb, Kb);
    prep_vt<<<dim3(LL / 64, 16), 256, 0, stream>>>(V, Vt);

    attnw_sums<<<dim3(LL / 128, 16, 2), 512, 0, stream>>>(Qb, Kb, Ssum);
    attnw_write<<<dim3(LL / 64, 16), 256, 0, stream>>>(Qb, Kb, Ssum, out2);
    sdpa_kernel<<<dim3(LL / 16, 16), 256, 0, stream>>>(Qb, Kb, Vt, out1);
}

// Round 5
// 388.142 us; speedup vs baseline: 1.5064x; 1.1745x over previous
//
#include <hip/hip_runtime.h>
#include <hip/hip_bf16.h>

#define LL 2048
#define DD 64

typedef __attribute__((ext_vector_type(4))) float f32x4;
typedef __attribute__((ext_vector_type(8))) short short8;
typedef __attribute__((ext_vector_type(4))) short short4v;

#define S1 0.18033688011112042f   /* 0.125 * log2(e) */
#define S2 23.083120654223414f    /* 16 * log2(e) */

static __device__ __forceinline__ short f2bf(float f) {
    union { float f; unsigned u; } v; v.f = f;
    unsigned r = v.u + 0x7fffu + ((v.u >> 16) & 1u);
    return (short)(r >> 16);
}

// ---------------- prep: fp32 -> bf16 (Q, K) ----------------
__global__ __launch_bounds__(256)
void prep_cvt(const float* __restrict__ Q, const float* __restrict__ K,
              short* __restrict__ Qb, short* __restrict__ Kb) {
    const float* src = blockIdx.y ? K : Q;
    short* dst = blockIdx.y ? Kb : Qb;
    size_t i = ((size_t)blockIdx.x * 256 + threadIdx.x) * 4;
    f32x4 v = *(const f32x4*)(src + i);
    short4v o;
    o[0] = f2bf(v[0]); o[1] = f2bf(v[1]); o[2] = f2bf(v[2]); o[3] = f2bf(v[3]);
    *(short4v*)(dst + i) = o;
}

// ---------------- prep: V [bh][s][d] -> Vt bf16 [bh][d][s] ----------------
__global__ __launch_bounds__(256)
void prep_vt(const float* __restrict__ V, short* __restrict__ Vt) {
    const int bh = blockIdx.y;
    const int s0 = blockIdx.x * 64;
    const int sl = threadIdx.x & 63;
    const int d0 = threadIdx.x >> 6;
    const float* Vs = V + (size_t)bh * LL * DD;
    short* Vd = Vt + (size_t)bh * DD * LL;
#pragma unroll
    for (int i = 0; i < 16; ++i) {
        int d = d0 + i * 4;
        Vd[(size_t)d * LL + s0 + sl] = f2bf(Vs[(size_t)(s0 + sl) * DD + d]);
    }
}

// ================= out2 two-pass (r3, proven) =================
// Sums parked in out1 (S writes, W reads, sdpa overwrites LAST).

// ---- Kernel S: row sums of exp(X X^T / 8 - 16), X in {Q, K} ----
__global__ __launch_bounds__(512, 4)
void attnw_sums(const short* __restrict__ Qb, const short* __restrict__ Kb,
                float* __restrict__ Ssum) {
    const int bh = blockIdx.y;
    const int mat = blockIdx.z;
    const int r0 = blockIdx.x * 128;
    const int tid = threadIdx.x;
    const int lane = tid & 63;
    const int wid = tid >> 6;   // 0..7
    const int q = lane >> 4;
    const int c0 = lane & 15;

    __shared__ short8 stg[512];   // 64 cols x 64 d, swizzled

    const short* X = (mat ? Kb : Qb) + (size_t)bh * LL * DD;
    float* Sd = Ssum + ((size_t)mat * 16 + bh) * LL;

    const int rw = r0 + wid * 16;
    const short8 a0 = *(const short8*)(X + (size_t)(rw + c0) * DD + q * 8);
    const short8 a1 = *(const short8*)(X + (size_t)(rw + c0) * DD + 32 + q * 8);

    const int sc = tid >> 3;        // staging col 0..63
    const int sd = tid & 7;         // staging d-octet 0..7
    const int sslot = sc * 8 + (sd ^ (sc & 7));

    float sum[4] = {0.f, 0.f, 0.f, 0.f};
    short8 rst = *(const short8*)(X + (size_t)sc * DD + sd * 8);
    for (int i = 0; i < 32; ++i) {
        __syncthreads();
        stg[sslot] = rst;
        __syncthreads();
        if (i + 1 < 32)
            rst = *(const short8*)(X + (size_t)((i + 1) * 64 + sc) * DD + sd * 8);
#pragma unroll
        for (int h = 0; h < 4; ++h) {
            const int col = h * 16 + c0;
            short8 b0 = stg[col * 8 + (q ^ (c0 & 7))];
            short8 b1 = stg[col * 8 + ((q + 4) ^ (c0 & 7))];
            f32x4 z = {0.f, 0.f, 0.f, 0.f};
            z = __builtin_amdgcn_mfma_f32_16x16x32_bf16(a0, b0, z, 0, 0, 0);
            z = __builtin_amdgcn_mfma_f32_16x16x32_bf16(a1, b1, z, 0, 0, 0);
#pragma unroll
            for (int r = 0; r < 4; ++r)
                sum[r] += __builtin_amdgcn_exp2f(z[r] * S1 - S2);
        }
    }
#pragma unroll
    for (int off = 1; off < 16; off <<= 1)
#pragma unroll
        for (int r = 0; r < 4; ++r) sum[r] += __shfl_xor(sum[r], off, 64);
    if (c0 == 0) {
#pragma unroll
        for (int r = 0; r < 4; ++r) Sd[rw + q * 4 + r] = sum[r];
    }
}

// ---- Kernel W: out2 = exp(QQ^T/8-16)*rclQ + exp(KK^T/8-16)*rclK ----
__global__ __launch_bounds__(256, 4)
void attnw_write(const short* __restrict__ Qb, const short* __restrict__ Kb,
                 const float* __restrict__ Ssum, float* __restrict__ out2) {
    const int bh = blockIdx.y;
    const int r0 = blockIdx.x * 64;
    const int tid = threadIdx.x;
    const int lane = tid & 63;
    const int wid = tid >> 6;   // 0..3
    const int q = lane >> 4;
    const int c0 = lane & 15;

    __shared__ short8 stgQ[256];               // 32 cols x 64 d, swizzled
    __shared__ short8 stgK[256];
    __shared__ __align__(16) float ob[4][16][36];   // wave-private bounce

    const short* Qh = Qb + (size_t)bh * LL * DD;
    const short* Kh = Kb + (size_t)bh * LL * DD;
    const float* Sq = Ssum + (size_t)bh * LL;
    const float* Sk = Ssum + (size_t)(16 + bh) * LL;

    const int rw = r0 + wid * 16;
    const short8 aq0 = *(const short8*)(Qh + (size_t)(rw + c0) * DD + q * 8);
    const short8 aq1 = *(const short8*)(Qh + (size_t)(rw + c0) * DD + 32 + q * 8);
    const short8 ak0 = *(const short8*)(Kh + (size_t)(rw + c0) * DD + q * 8);
    const short8 ak1 = *(const short8*)(Kh + (size_t)(rw + c0) * DD + 32 + q * 8);

    float rclQ[4], rclK[4];
#pragma unroll
    for (int r = 0; r < 4; ++r) {
        rclQ[r] = 1.0f / Sq[rw + q * 4 + r];
        rclK[r] = 1.0f / Sk[rw + q * 4 + r];
    }

    const int sc = tid >> 3;   // staging col 0..31
    const int sd = tid & 7;
    const int sslot = sc * 8 + (sd ^ (sc & 7));

    float* outp = out2 + (size_t)bh * LL * LL + (size_t)rw * LL;

    short8 rq = *(const short8*)(Qh + (size_t)sc * DD + sd * 8);
    short8 rk = *(const short8*)(Kh + (size_t)sc * DD + sd * 8);
    for (int i = 0; i < 64; ++i) {
        __syncthreads();
        stgQ[sslot] = rq;
        stgK[sslot] = rk;
        __syncthreads();
        if (i + 1 < 64) {
            rq = *(const short8*)(Qh + (size_t)((i + 1) * 32 + sc) * DD + sd * 8);
            rk = *(const short8*)(Kh + (size_t)((i + 1) * 32 + sc) * DD + sd * 8);
        }
#pragma unroll
        for (int h = 0; h < 2; ++h) {
            const int col = h * 16 + c0;
            short8 bq0 = stgQ[col * 8 + (q ^ (c0 & 7))];
            short8 bq1 = stgQ[col * 8 + ((q + 4) ^ (c0 & 7))];
            short8 bk0 = stgK[col * 8 + (q ^ (c0 & 7))];
            short8 bk1 = stgK[col * 8 + ((q + 4) ^ (c0 & 7))];
            f32x4 zq = {0.f, 0.f, 0.f, 0.f}, zk = {0.f, 0.f, 0.f, 0.f};
            zq = __builtin_amdgcn_mfma_f32_16x16x32_bf16(aq0, bq0, zq, 0, 0, 0);
            zq = __builtin_amdgcn_mfma_f32_16x16x32_bf16(aq1, bq1, zq, 0, 0, 0);
            zk = __builtin_amdgcn_mfma_f32_16x16x32_bf16(ak0, bk0, zk, 0, 0, 0);
            zk = __builtin_amdgcn_mfma_f32_16x16x32_bf16(ak1, bk1, zk, 0, 0, 0);
#pragma unroll
            for (int r = 0; r < 4; ++r) {
                float v = __builtin_amdgcn_exp2f(zq[r] * S1 - S2) * rclQ[r]
                        + __builtin_amdgcn_exp2f(zk[r] * S1 - S2) * rclK[r];
                ob[wid][q * 4 + r][h * 16 + c0] = v;
            }
        }
        // wave-private bounce -> 16 rows x 32 cols = full 128B lines
#pragma unroll
        for (int j = 0; j < 2; ++j) {
            int idx = lane + j * 64;
            int row = idx >> 3;
            int c8 = idx & 7;
            f32x4 v = *(const f32x4*)(&ob[wid][row][c8 * 4]);
            __builtin_nontemporal_store(
                v, (f32x4*)&outp[(size_t)row * LL + i * 32 + c8 * 4]);
        }
    }
}

// ---------------- Kernel 1 (r4 restructure): out1 = softmax(QK^T/8) V ----------------
// Port of the proven attnw_write structure: 64 rows/wg, ROW-split waves
// (wave = 16 rows x all 2048 cols), K and Vt LDS-staged (XOR-swizzled, panel
// read ONCE per wg instead of once per wave-column: 4x less L2 traffic, LDS
// latency replaces L2 latency on the critical path), chunk i+1 register
// prefetch issued before chunk i compute. Row-ownership kills the cross-wave
// sum combine + obuf reduction: softmax reduce is wave-internal shuffles,
// epilogue is wave-private (no barriers).
__global__ __launch_bounds__(256, 4)
void sdpa_kernel(const short* __restrict__ Qb, const short* __restrict__ Kb,
                 const short* __restrict__ Vt, float* __restrict__ out1) {
    const int bh = blockIdx.y;
    const int r0 = blockIdx.x * 64;
    const int tid = threadIdx.x;
    const int lane = tid & 63;
    const int wid = tid >> 6;   // 0..3: row-block owner
    const int q = lane >> 4;
    const int c0 = lane & 15;

    __shared__ short8 stgK[256];   // 32 cols x 8 d-octets, slot = c*8 + (do ^ (c&7))
    __shared__ short8 stgV[256];   // 64 d x 4 s-octets,   slot = d*4 + (so ^ (d&3))
    __shared__ __align__(16) short pbuf[4][16][40];   // [wave][m][k], row stride 80B
    __shared__ float obuf[4][1024];                   // wave-private store bounce

    const short* Qh = Qb + (size_t)bh * LL * DD;
    const short* Kh = Kb + (size_t)bh * LL * DD;
    const short* Vh = Vt + (size_t)bh * DD * LL;

    const int rw = r0 + wid * 16;
    const short8 a0 = *(const short8*)(Qh + (size_t)(rw + c0) * DD + q * 8);
    const short8 a1 = *(const short8*)(Qh + (size_t)(rw + c0) * DD + 32 + q * 8);

    f32x4 oacc[4];
#pragma unroll
    for (int dt = 0; dt < 4; ++dt) { f32x4 z = {0.f,0.f,0.f,0.f}; oacc[dt] = z; }
    float sum[4] = {0.f, 0.f, 0.f, 0.f};

    // staging thread roles
    const int sc = tid >> 3;          // K col 0..31
    const int sdo = tid & 7;          // K d-octet 0..7
    const int kslot = sc * 8 + (sdo ^ (sc & 7));
    const int vd = tid >> 2;          // V d 0..63
    const int vs = tid & 3;           // V s-octet 0..3
    const int vslot = vd * 4 + (vs ^ (vd & 3));

    short8 rk = *(const short8*)(Kh + (size_t)sc * DD + sdo * 8);
    short8 rv = *(const short8*)(Vh + (size_t)vd * LL + vs * 8);

    for (int i = 0; i < 64; ++i) {
        __syncthreads();
        stgK[kslot] = rk;
        stgV[vslot] = rv;
        __syncthreads();
        if (i + 1 < 64) {
            rk = *(const short8*)(Kh + (size_t)((i + 1) * 32 + sc) * DD + sdo * 8);
            rv = *(const short8*)(Vh + (size_t)vd * LL + (i + 1) * 32 + vs * 8);
        }
        // scores 16 rows x 32 cols -> exp -> bf16 into pbuf (A-frag source layout)
#pragma unroll
        for (int h = 0; h < 2; ++h) {
            const int col = h * 16 + c0;
            short8 b0 = stgK[col * 8 + (q ^ (col & 7))];
            short8 b1 = stgK[col * 8 + ((q + 4) ^ (col & 7))];
            f32x4 z = {0.f, 0.f, 0.f, 0.f};
            z = __builtin_amdgcn_mfma_f32_16x16x32_bf16(a0, b0, z, 0, 0, 0);
            z = __builtin_amdgcn_mfma_f32_16x16x32_bf16(a1, b1, z, 0, 0, 0);
#pragma unroll
            for (int r = 0; r < 4; ++r) {
                float e = __builtin_amdgcn_exp2f(z[r] * S1);
                sum[r] += e;
                pbuf[wid][q * 4 + r][h * 16 + c0] = f2bf(e);
            }
        }
        // read back as A-frag (wave-internal LDS round-trip, in-order per wave)
        short8 ap = *(const short8*)(&pbuf[wid][c0][q * 8]);
        // V B-frags from swizzled LDS: lane (c0=d-col, q=s-octet)
#pragma unroll
        for (int dt = 0; dt < 4; ++dt) {
            const int d = dt * 16 + c0;
            short8 bv = stgV[d * 4 + (q ^ (d & 3))];
            oacc[dt] = __builtin_amdgcn_mfma_f32_16x16x32_bf16(ap, bv, oacc[dt], 0, 0, 0);
        }
    }

    // ---- wave-internal row-sum (rows live entirely in this wave) ----
#pragma unroll
    for (int off = 1; off < 16; off <<= 1)
#pragma unroll
        for (int r = 0; r < 4; ++r) sum[r] += __shfl_xor(sum[r], off, 64);
    float rcl[4];
#pragma unroll
    for (int r = 0; r < 4; ++r) rcl[r] = 1.0f / sum[r];

    // ---- wave-private bounce -> coalesced f32x4 stores (no barriers) ----
#pragma unroll
    for (int dt = 0; dt < 4; ++dt)
#pragma unroll
        for (int r = 0; r < 4; ++r)
            obuf[wid][(q * 4 + r) * 64 + dt * 16 + c0] = oacc[dt][r] * rcl[r];
    float* o1 = out1 + (size_t)bh * LL * DD + (size_t)rw * DD;
#pragma unroll
    for (int j = 0; j < 4; ++j) {
        int e4 = lane + j * 64;    // f32x4 index within this wave's 16x64 block
        f32x4 v = *(const f32x4*)(&obuf[wid][e4 * 4]);
        *(f32x4*)(o1 + e4 * 4) = v;
    }
}

extern "C" void kernel_launch(void* const* d_in, const int* in_sizes, int n_in,
                              void* d_out, int out_size, void* d_ws, size_t ws_size,
                              hipStream_t stream) {
    const float* Q = (const float*)d_in[0];
    const float* K = (const float*)d_in[1];
    const float* V = (const float*)d_in[2];
    float* out1 = (float*)d_out;                          // [2,8,2048,64]
    float* out2 = out1 + (size_t)16 * LL * DD;            // [2,8,2048,2048]

    const size_t N = (size_t)16 * LL * DD;                // 2,097,152 per tensor
    short* Qb = (short*)d_ws;
    short* Kb = Qb + N;
    short* Vt = Kb + N;

    // Row sums live in the out1 region: attnw_sums writes 256 KB, attnw_write
    // reads it, then sdpa_kernel (launched LAST) overwrites out1 entirely.
    float* Ssum = out1;

    prep_cvt<<<dim3((unsigned)(N / 1024), 2), 256, 0, stream>>>(Q, K, Qb, Kb);
    prep_vt<<<dim3(LL / 64, 16), 256, 0, stream>>>(V, Vt);

    attnw_sums<<<dim3(LL / 128, 16, 2), 512, 0, stream>>>(Qb, Kb, Ssum);
    attnw_write<<<dim3(LL / 64, 16), 256, 0, stream>>>(Qb, Kb, Ssum, out2);
    sdpa_kernel<<<dim3(LL / 64, 16), 256, 0, stream>>>(Qb, Kb, Vt, out1);
}

// Round 6
// 382.474 us; speedup vs baseline: 1.5288x; 1.0148x over previous
//
#include <hip/hip_runtime.h>
#include <hip/hip_bf16.h>

#define LL 2048
#define DD 64

typedef __attribute__((ext_vector_type(4))) float f32x4;
typedef __attribute__((ext_vector_type(8))) short short8;
typedef __attribute__((ext_vector_type(4))) short short4v;

#define S1 0.18033688011112042f   /* 0.125 * log2(e) */
#define S2 23.083120654223414f    /* 16 * log2(e) */

static __device__ __forceinline__ short f2bf(float f) {
    union { float f; unsigned u; } v; v.f = f;
    unsigned r = v.u + 0x7fffu + ((v.u >> 16) & 1u);
    return (short)(r >> 16);
}

// ---------------- prep: fp32 -> bf16 (Q, K) ----------------
__global__ __launch_bounds__(256)
void prep_cvt(const float* __restrict__ Q, const float* __restrict__ K,
              short* __restrict__ Qb, short* __restrict__ Kb) {
    const float* src = blockIdx.y ? K : Q;
    short* dst = blockIdx.y ? Kb : Qb;
    size_t i = ((size_t)blockIdx.x * 256 + threadIdx.x) * 4;
    f32x4 v = *(const f32x4*)(src + i);
    short4v o;
    o[0] = f2bf(v[0]); o[1] = f2bf(v[1]); o[2] = f2bf(v[2]); o[3] = f2bf(v[3]);
    *(short4v*)(dst + i) = o;
}

// ---------------- prep: V [bh][s][d] -> Vt bf16 [bh][d][s] ----------------
__global__ __launch_bounds__(256)
void prep_vt(const float* __restrict__ V, short* __restrict__ Vt) {
    const int bh = blockIdx.y;
    const int s0 = blockIdx.x * 64;
    const int sl = threadIdx.x & 63;
    const int d0 = threadIdx.x >> 6;
    const float* Vs = V + (size_t)bh * LL * DD;
    short* Vd = Vt + (size_t)bh * DD * LL;
#pragma unroll
    for (int i = 0; i < 16; ++i) {
        int d = d0 + i * 4;
        Vd[(size_t)d * LL + s0 + sl] = f2bf(Vs[(size_t)(s0 + sl) * DD + d]);
    }
}

// ================= out2 two-pass (r3, proven) =================
// Sums parked in out1 (S writes, W reads, sdpa overwrites LAST).

// ---- Kernel S: row sums of exp(X X^T / 8 - 16), X in {Q, K} ----
__global__ __launch_bounds__(512, 4)
void attnw_sums(const short* __restrict__ Qb, const short* __restrict__ Kb,
                float* __restrict__ Ssum) {
    const int bh = blockIdx.y;
    const int mat = blockIdx.z;
    const int r0 = blockIdx.x * 128;
    const int tid = threadIdx.x;
    const int lane = tid & 63;
    const int wid = tid >> 6;   // 0..7
    const int q = lane >> 4;
    const int c0 = lane & 15;

    __shared__ short8 stg[512];   // 64 cols x 64 d, swizzled

    const short* X = (mat ? Kb : Qb) + (size_t)bh * LL * DD;
    float* Sd = Ssum + ((size_t)mat * 16 + bh) * LL;

    const int rw = r0 + wid * 16;
    const short8 a0 = *(const short8*)(X + (size_t)(rw + c0) * DD + q * 8);
    const short8 a1 = *(const short8*)(X + (size_t)(rw + c0) * DD + 32 + q * 8);

    const int sc = tid >> 3;        // staging col 0..63
    const int sd = tid & 7;         // staging d-octet 0..7
    const int sslot = sc * 8 + (sd ^ (sc & 7));

    float sum[4] = {0.f, 0.f, 0.f, 0.f};
    short8 rst = *(const short8*)(X + (size_t)sc * DD + sd * 8);
    for (int i = 0; i < 32; ++i) {
        __syncthreads();
        stg[sslot] = rst;
        __syncthreads();
        if (i + 1 < 32)
            rst = *(const short8*)(X + (size_t)((i + 1) * 64 + sc) * DD + sd * 8);
#pragma unroll
        for (int h = 0; h < 4; ++h) {
            const int col = h * 16 + c0;
            short8 b0 = stg[col * 8 + (q ^ (c0 & 7))];
            short8 b1 = stg[col * 8 + ((q + 4) ^ (c0 & 7))];
            f32x4 z = {0.f, 0.f, 0.f, 0.f};
            z = __builtin_amdgcn_mfma_f32_16x16x32_bf16(a0, b0, z, 0, 0, 0);
            z = __builtin_amdgcn_mfma_f32_16x16x32_bf16(a1, b1, z, 0, 0, 0);
#pragma unroll
            for (int r = 0; r < 4; ++r)
                sum[r] += __builtin_amdgcn_exp2f(z[r] * S1 - S2);
        }
    }
#pragma unroll
    for (int off = 1; off < 16; off <<= 1)
#pragma unroll
        for (int r = 0; r < 4; ++r) sum[r] += __shfl_xor(sum[r], off, 64);
    if (c0 == 0) {
#pragma unroll
        for (int r = 0; r < 4; ++r) Sd[rw + q * 4 + r] = sum[r];
    }
}

// ---- Kernel W: out2 = exp(QQ^T/8-16)*rclQ + exp(KK^T/8-16)*rclK ----
// r5: 64-col chunks (was 32): 32 iters x 2 barriers = 64 barrier drains per wg
// (was 128). Same total MFMA/exp/stores; staging 8KB/matrix, ob 17.4KB ->
// 33.8KB LDS, still 4 wg/CU.
__global__ __launch_bounds__(256, 4)
void attnw_write(const short* __restrict__ Qb, const short* __restrict__ Kb,
                 const float* __restrict__ Ssum, float* __restrict__ out2) {
    const int bh = blockIdx.y;
    const int r0 = blockIdx.x * 64;
    const int tid = threadIdx.x;
    const int lane = tid & 63;
    const int wid = tid >> 6;   // 0..3
    const int q = lane >> 4;
    const int c0 = lane & 15;

    __shared__ short8 stgQ[512];               // 64 cols x 8 d-octets, swizzled
    __shared__ short8 stgK[512];
    __shared__ __align__(16) float ob[4][16][68];   // wave-private bounce

    const short* Qh = Qb + (size_t)bh * LL * DD;
    const short* Kh = Kb + (size_t)bh * LL * DD;
    const float* Sq = Ssum + (size_t)bh * LL;
    const float* Sk = Ssum + (size_t)(16 + bh) * LL;

    const int rw = r0 + wid * 16;
    const short8 aq0 = *(const short8*)(Qh + (size_t)(rw + c0) * DD + q * 8);
    const short8 aq1 = *(const short8*)(Qh + (size_t)(rw + c0) * DD + 32 + q * 8);
    const short8 ak0 = *(const short8*)(Kh + (size_t)(rw + c0) * DD + q * 8);
    const short8 ak1 = *(const short8*)(Kh + (size_t)(rw + c0) * DD + 32 + q * 8);

    float rclQ[4], rclK[4];
#pragma unroll
    for (int r = 0; r < 4; ++r) {
        rclQ[r] = 1.0f / Sq[rw + q * 4 + r];
        rclK[r] = 1.0f / Sk[rw + q * 4 + r];
    }

    const int sc = tid >> 3;   // staging col 0..31 (also col+32)
    const int sd = tid & 7;
    const int slot0 = sc * 8 + (sd ^ (sc & 7));
    const int slot1 = (sc + 32) * 8 + (sd ^ (sc & 7));   // (sc+32)&7 == sc&7

    float* outp = out2 + (size_t)bh * LL * LL + (size_t)rw * LL;

    short8 rq0 = *(const short8*)(Qh + (size_t)sc * DD + sd * 8);
    short8 rq1 = *(const short8*)(Qh + (size_t)(sc + 32) * DD + sd * 8);
    short8 rk0 = *(const short8*)(Kh + (size_t)sc * DD + sd * 8);
    short8 rk1 = *(const short8*)(Kh + (size_t)(sc + 32) * DD + sd * 8);
    for (int i = 0; i < 32; ++i) {
        __syncthreads();
        stgQ[slot0] = rq0; stgQ[slot1] = rq1;
        stgK[slot0] = rk0; stgK[slot1] = rk1;
        __syncthreads();
        if (i + 1 < 32) {
            rq0 = *(const short8*)(Qh + (size_t)((i + 1) * 64 + sc) * DD + sd * 8);
            rq1 = *(const short8*)(Qh + (size_t)((i + 1) * 64 + sc + 32) * DD + sd * 8);
            rk0 = *(const short8*)(Kh + (size_t)((i + 1) * 64 + sc) * DD + sd * 8);
            rk1 = *(const short8*)(Kh + (size_t)((i + 1) * 64 + sc + 32) * DD + sd * 8);
        }
#pragma unroll
        for (int h = 0; h < 4; ++h) {
            const int col = h * 16 + c0;
            short8 bq0 = stgQ[col * 8 + (q ^ (c0 & 7))];
            short8 bq1 = stgQ[col * 8 + ((q + 4) ^ (c0 & 7))];
            short8 bk0 = stgK[col * 8 + (q ^ (c0 & 7))];
            short8 bk1 = stgK[col * 8 + ((q + 4) ^ (c0 & 7))];
            f32x4 zq = {0.f, 0.f, 0.f, 0.f}, zk = {0.f, 0.f, 0.f, 0.f};
            zq = __builtin_amdgcn_mfma_f32_16x16x32_bf16(aq0, bq0, zq, 0, 0, 0);
            zq = __builtin_amdgcn_mfma_f32_16x16x32_bf16(aq1, bq1, zq, 0, 0, 0);
            zk = __builtin_amdgcn_mfma_f32_16x16x32_bf16(ak0, bk0, zk, 0, 0, 0);
            zk = __builtin_amdgcn_mfma_f32_16x16x32_bf16(ak1, bk1, zk, 0, 0, 0);
#pragma unroll
            for (int r = 0; r < 4; ++r) {
                float v = __builtin_amdgcn_exp2f(zq[r] * S1 - S2) * rclQ[r]
                        + __builtin_amdgcn_exp2f(zk[r] * S1 - S2) * rclK[r];
                ob[wid][q * 4 + r][h * 16 + c0] = v;
            }
        }
        // wave-private bounce -> 16 rows x 64 cols = full 128B lines
#pragma unroll
        for (int j = 0; j < 4; ++j) {
            int idx = lane + j * 64;        // 0..255 f32x4
            int row = idx >> 4;             // 0..15
            int c8 = idx & 15;              // 0..15
            f32x4 v = *(const f32x4*)(&ob[wid][row][c8 * 4]);
            __builtin_nontemporal_store(
                v, (f32x4*)&outp[(size_t)row * LL + i * 64 + c8 * 4]);
        }
    }
}

// ---------------- Kernel 1: out1 = softmax(QK^T/8) V ----------------
// r4 structure + r5 64-col chunks: 32 iters x 2 barriers = 64 drains per wg
// (was 128). obuf dropped (direct 64B-segment stores; out1 is only 8MB) so
// LDS = 25.6KB keeps 4 wg/CU.
__global__ __launch_bounds__(256, 4)
void sdpa_kernel(const short* __restrict__ Qb, const short* __restrict__ Kb,
                 const short* __restrict__ Vt, float* __restrict__ out1) {
    const int bh = blockIdx.y;
    const int r0 = blockIdx.x * 64;
    const int tid = threadIdx.x;
    const int lane = tid & 63;
    const int wid = tid >> 6;   // 0..3: row-block owner
    const int q = lane >> 4;
    const int c0 = lane & 15;

    __shared__ short8 stgK[512];   // 64 cols x 8 d-octets, slot = c*8 + (do ^ (c&7))
    __shared__ short8 stgV[512];   // 64 d x 8 s-octets,   slot = d*8 + (so ^ (d&7))
    __shared__ __align__(16) short pbuf[4][16][72];   // [wave][m][k], row stride 144B

    const short* Qh = Qb + (size_t)bh * LL * DD;
    const short* Kh = Kb + (size_t)bh * LL * DD;
    const short* Vh = Vt + (size_t)bh * DD * LL;

    const int rw = r0 + wid * 16;
    const short8 a0 = *(const short8*)(Qh + (size_t)(rw + c0) * DD + q * 8);
    const short8 a1 = *(const short8*)(Qh + (size_t)(rw + c0) * DD + 32 + q * 8);

    f32x4 oacc[4];
#pragma unroll
    for (int dt = 0; dt < 4; ++dt) { f32x4 z = {0.f,0.f,0.f,0.f}; oacc[dt] = z; }
    float sum[4] = {0.f, 0.f, 0.f, 0.f};

    // staging thread roles (2 slots each, 512 slots / 256 threads)
    const int kc = tid >> 3;          // K col 0..31 (also +32)
    const int ko = tid & 7;           // K d-octet
    const int kslot0 = kc * 8 + (ko ^ (kc & 7));
    const int kslot1 = (kc + 32) * 8 + (ko ^ (kc & 7));
    const int vd = tid >> 2;          // V d 0..63
    const int vs = tid & 3;           // V s-octet (also +4)
    const int vslot0 = vd * 8 + (vs ^ (vd & 7));
    const int vslot1 = vd * 8 + ((vs + 4) ^ (vd & 7));

    short8 rk0 = *(const short8*)(Kh + (size_t)kc * DD + ko * 8);
    short8 rk1 = *(const short8*)(Kh + (size_t)(kc + 32) * DD + ko * 8);
    short8 rv0 = *(const short8*)(Vh + (size_t)vd * LL + vs * 8);
    short8 rv1 = *(const short8*)(Vh + (size_t)vd * LL + vs * 8 + 32);

    for (int i = 0; i < 32; ++i) {
        __syncthreads();
        stgK[kslot0] = rk0; stgK[kslot1] = rk1;
        stgV[vslot0] = rv0; stgV[vslot1] = rv1;
        __syncthreads();
        if (i + 1 < 32) {
            rk0 = *(const short8*)(Kh + (size_t)((i + 1) * 64 + kc) * DD + ko * 8);
            rk1 = *(const short8*)(Kh + (size_t)((i + 1) * 64 + kc + 32) * DD + ko * 8);
            rv0 = *(const short8*)(Vh + (size_t)vd * LL + (i + 1) * 64 + vs * 8);
            rv1 = *(const short8*)(Vh + (size_t)vd * LL + (i + 1) * 64 + vs * 8 + 32);
        }
        // scores 16 rows x 64 cols -> exp -> bf16 into pbuf (A-frag source layout)
#pragma unroll
        for (int h = 0; h < 4; ++h) {
            const int col = h * 16 + c0;
            short8 b0 = stgK[col * 8 + (q ^ (c0 & 7))];
            short8 b1 = stgK[col * 8 + ((q + 4) ^ (c0 & 7))];
            f32x4 z = {0.f, 0.f, 0.f, 0.f};
            z = __builtin_amdgcn_mfma_f32_16x16x32_bf16(a0, b0, z, 0, 0, 0);
            z = __builtin_amdgcn_mfma_f32_16x16x32_bf16(a1, b1, z, 0, 0, 0);
#pragma unroll
            for (int r = 0; r < 4; ++r) {
                float e = __builtin_amdgcn_exp2f(z[r] * S1);
                sum[r] += e;
                pbuf[wid][q * 4 + r][h * 16 + c0] = f2bf(e);
            }
        }
        // read back as A-frags (wave-internal LDS round-trip, in-order per wave)
        short8 ap0 = *(const short8*)(&pbuf[wid][c0][q * 8]);
        short8 ap1 = *(const short8*)(&pbuf[wid][c0][32 + q * 8]);
        // V B-frags from swizzled LDS: lane (c0 -> d-col, q -> s-octet)
#pragma unroll
        for (int dt = 0; dt < 4; ++dt) {
            const int d = dt * 16 + c0;
            short8 bv0 = stgV[d * 8 + (q ^ (d & 7))];
            short8 bv1 = stgV[d * 8 + ((q + 4) ^ (d & 7))];
            oacc[dt] = __builtin_amdgcn_mfma_f32_16x16x32_bf16(ap0, bv0, oacc[dt], 0, 0, 0);
            oacc[dt] = __builtin_amdgcn_mfma_f32_16x16x32_bf16(ap1, bv1, oacc[dt], 0, 0, 0);
        }
    }

    // ---- wave-internal row-sum (rows live entirely in this wave) ----
#pragma unroll
    for (int off = 1; off < 16; off <<= 1)
#pragma unroll
        for (int r = 0; r < 4; ++r) sum[r] += __shfl_xor(sum[r], off, 64);
    float rcl[4];
#pragma unroll
    for (int r = 0; r < 4; ++r) rcl[r] = 1.0f / sum[r];

    // ---- direct stores: lane (q,r,c0) -> O[rw+q*4+r][dt*16+c0] ----
    float* o1 = out1 + (size_t)bh * LL * DD + (size_t)rw * DD;
#pragma unroll
    for (int dt = 0; dt < 4; ++dt)
#pragma unroll
        for (int r = 0; r < 4; ++r)
            o1[(size_t)(q * 4 + r) * DD + dt * 16 + c0] = oacc[dt][r] * rcl[r];
}

extern "C" void kernel_launch(void* const* d_in, const int* in_sizes, int n_in,
                              void* d_out, int out_size, void* d_ws, size_t ws_size,
                              hipStream_t stream) {
    const float* Q = (const float*)d_in[0];
    const float* K = (const float*)d_in[1];
    const float* V = (const float*)d_in[2];
    float* out1 = (float*)d_out;                          // [2,8,2048,64]
    float* out2 = out1 + (size_t)16 * LL * DD;            // [2,8,2048,2048]

    const size_t N = (size_t)16 * LL * DD;                // 2,097,152 per tensor
    short* Qb = (short*)d_ws;
    short* Kb = Qb + N;
    short* Vt = Kb + N;

    // Row sums live in the out1 region: attnw_sums writes 256 KB, attnw_write
    // reads it, then sdpa_kernel (launched LAST) overwrites out1 entirely.
    float* Ssum = out1;

    prep_cvt<<<dim3((unsigned)(N / 1024), 2), 256, 0, stream>>>(Q, K, Qb, Kb);
    prep_vt<<<dim3(LL / 64, 16), 256, 0, stream>>>(V, Vt);

    attnw_sums<<<dim3(LL / 128, 16, 2), 512, 0, stream>>>(Qb, Kb, Ssum);
    attnw_write<<<dim3(LL / 64, 16), 256, 0, stream>>>(Qb, Kb, Ssum, out2);
    sdpa_kernel<<<dim3(LL / 64, 16), 256, 0, stream>>>(Qb, Kb, Vt, out1);
}